// Round 1
// baseline (456.494 us; speedup 1.0000x reference)
//
#include <hip/hip_runtime.h>

// HalfEdgeMeshPool: segment-mean of half-edge features into surviving groups.
// feat: [B, C, N] f32, gid: [B, N] i32 in [0,T), out: [B, C, T] f32.
static constexpr int B = 8;
static constexpr int C = 256;
static constexpr int N = 40000;
static constexpr int T = 20000;

// Phase 1: per-(b,t) counts via global int atomics. 320K atomics, trivial.
__global__ void __launch_bounds__(256) hemp_count_kernel(const int* __restrict__ gid,
                                                         int* __restrict__ counts) {
    int idx = blockIdx.x * 256 + threadIdx.x;
    if (idx < B * N) {
        int b = idx / N;
        atomicAdd(&counts[b * T + gid[idx]], 1);
    }
}

// Phase 2: one block per (b,c). LDS-privatized T-wide accumulator (80 KB),
// float4-vectorized streaming of the feature row, fused divide on writeout.
__global__ void __launch_bounds__(256) hemp_pool_kernel(const float* __restrict__ feat,
                                                        const int* __restrict__ gid,
                                                        const int* __restrict__ counts,
                                                        float* __restrict__ out) {
    extern __shared__ float lds_sum[];  // T floats = 80000 bytes
    const int tid = threadIdx.x;
    const int b = blockIdx.x >> 8;   // blocks with same b adjacent -> gid[b] hot in L2
    const int c = blockIdx.x & 255;

    for (int t = tid; t < T; t += 256) lds_sum[t] = 0.0f;
    __syncthreads();

    const float4* __restrict__ f4 =
        reinterpret_cast<const float4*>(feat + (size_t)(b * C + c) * N);
    const int4* __restrict__ g4 =
        reinterpret_cast<const int4*>(gid + (size_t)b * N);
    for (int i = tid; i < N / 4; i += 256) {
        float4 v = f4[i];
        int4 g = g4[i];
        atomicAdd(&lds_sum[g.x], v.x);
        atomicAdd(&lds_sum[g.y], v.y);
        atomicAdd(&lds_sum[g.z], v.z);
        atomicAdd(&lds_sum[g.w], v.w);
    }
    __syncthreads();

    const int* __restrict__ cnt_b = counts + (size_t)b * T;
    float* __restrict__ out_bc = out + (size_t)(b * C + c) * T;
    for (int t = tid; t < T; t += 256) {
        float cnt = (float)cnt_b[t];
        out_bc[t] = lds_sum[t] / fmaxf(cnt, 1.0f);
    }
}

extern "C" void kernel_launch(void* const* d_in, const int* in_sizes, int n_in,
                              void* d_out, int out_size, void* d_ws, size_t ws_size,
                              hipStream_t stream) {
    const float* feat = (const float*)d_in[0];
    const int* gid = (const int*)d_in[1];
    float* out = (float*)d_out;
    int* counts = (int*)d_ws;  // B*T ints = 640 KB

    hipMemsetAsync(counts, 0, (size_t)B * T * sizeof(int), stream);
    hemp_count_kernel<<<(B * N + 255) / 256, 256, 0, stream>>>(gid, counts);

    const size_t lds_bytes = (size_t)T * sizeof(float);  // 80 KB > 64 KB default cap
    hipFuncSetAttribute(reinterpret_cast<const void*>(hemp_pool_kernel),
                        hipFuncAttributeMaxDynamicSharedMemorySize, (int)lds_bytes);
    hemp_pool_kernel<<<B * C, 256, lds_bytes, stream>>>(feat, gid, counts, out);
}

// Round 2
// 443.486 us; speedup vs baseline: 1.0293x; 1.0293x over previous
//
#include <hip/hip_runtime.h>

// HalfEdgeMeshPool: segment-mean of half-edge features into surviving groups.
// feat: [B, C, N] f32, gid: [B, N] i32 in [0,T), out: [B, C, T] f32.
static constexpr int B = 8;
static constexpr int C = 256;
static constexpr int N = 40000;
static constexpr int T = 20000;
static constexpr int BLK = 1024;   // 16 waves/block; 2 blocks/CU (80KB LDS) = 32 waves/CU

// Phase 1: per-(b,t) counts via global int atomics. 320K atomics, trivial.
__global__ void __launch_bounds__(256) hemp_count_kernel(const int* __restrict__ gid,
                                                         int* __restrict__ counts) {
    int idx = blockIdx.x * 256 + threadIdx.x;
    if (idx < B * N) {
        int b = idx / N;
        atomicAdd(&counts[b * T + gid[idx]], 1);
    }
}

// Phase 2: one block per (b,c). LDS-privatized T-wide accumulator (80 KB),
// float4 streaming, native ds_add_f32 via unsafeAtomicAdd, fused divide.
__global__ void __launch_bounds__(BLK) hemp_pool_kernel(const float* __restrict__ feat,
                                                        const int* __restrict__ gid,
                                                        const int* __restrict__ counts,
                                                        float* __restrict__ out) {
    extern __shared__ float lds_sum[];  // T floats = 80000 bytes
    const int tid = threadIdx.x;
    const int b = blockIdx.x >> 8;   // blocks with same b adjacent -> gid[b] hot in L2
    const int c = blockIdx.x & 255;

    float4* ls4 = reinterpret_cast<float4*>(lds_sum);
    for (int t = tid; t < T / 4; t += BLK)
        ls4[t] = make_float4(0.f, 0.f, 0.f, 0.f);
    __syncthreads();

    const float4* __restrict__ f4 =
        reinterpret_cast<const float4*>(feat + (size_t)(b * C + c) * N);
    const int4* __restrict__ g4 =
        reinterpret_cast<const int4*>(gid + (size_t)b * N);

    constexpr int n4 = N / 4;  // 10000
    int i = tid;
    // unroll-2: issue both load pairs before any LDS atomic -> deeper pipelining
    for (; i + BLK < n4; i += 2 * BLK) {
        float4 v0 = f4[i];
        int4 g0 = g4[i];
        float4 v1 = f4[i + BLK];
        int4 g1 = g4[i + BLK];
        unsafeAtomicAdd(&lds_sum[g0.x], v0.x);
        unsafeAtomicAdd(&lds_sum[g0.y], v0.y);
        unsafeAtomicAdd(&lds_sum[g0.z], v0.z);
        unsafeAtomicAdd(&lds_sum[g0.w], v0.w);
        unsafeAtomicAdd(&lds_sum[g1.x], v1.x);
        unsafeAtomicAdd(&lds_sum[g1.y], v1.y);
        unsafeAtomicAdd(&lds_sum[g1.z], v1.z);
        unsafeAtomicAdd(&lds_sum[g1.w], v1.w);
    }
    for (; i < n4; i += BLK) {
        float4 v = f4[i];
        int4 g = g4[i];
        unsafeAtomicAdd(&lds_sum[g.x], v.x);
        unsafeAtomicAdd(&lds_sum[g.y], v.y);
        unsafeAtomicAdd(&lds_sum[g.z], v.z);
        unsafeAtomicAdd(&lds_sum[g.w], v.w);
    }
    __syncthreads();

    const int4* __restrict__ cnt4 =
        reinterpret_cast<const int4*>(counts + (size_t)b * T);
    float4* __restrict__ out4 =
        reinterpret_cast<float4*>(out + (size_t)(b * C + c) * T);
    for (int t = tid; t < T / 4; t += BLK) {
        int4 cn = cnt4[t];
        float4 s = ls4[t];
        float4 r;
        r.x = s.x / fmaxf((float)cn.x, 1.0f);
        r.y = s.y / fmaxf((float)cn.y, 1.0f);
        r.z = s.z / fmaxf((float)cn.z, 1.0f);
        r.w = s.w / fmaxf((float)cn.w, 1.0f);
        out4[t] = r;
    }
}

extern "C" void kernel_launch(void* const* d_in, const int* in_sizes, int n_in,
                              void* d_out, int out_size, void* d_ws, size_t ws_size,
                              hipStream_t stream) {
    const float* feat = (const float*)d_in[0];
    const int* gid = (const int*)d_in[1];
    float* out = (float*)d_out;
    int* counts = (int*)d_ws;  // B*T ints = 640 KB

    hipMemsetAsync(counts, 0, (size_t)B * T * sizeof(int), stream);
    hemp_count_kernel<<<(B * N + 255) / 256, 256, 0, stream>>>(gid, counts);

    const size_t lds_bytes = (size_t)T * sizeof(float);  // 80 KB > 64 KB default cap
    hipFuncSetAttribute(reinterpret_cast<const void*>(hemp_pool_kernel),
                        hipFuncAttributeMaxDynamicSharedMemorySize, (int)lds_bytes);
    hemp_pool_kernel<<<B * C, BLK, lds_bytes, stream>>>(feat, gid, counts, out);
}